// Round 5
// baseline (509.324 us; speedup 1.0000x reference)
//
#include <hip/hip_runtime.h>
#include <cstdint>

#define C_ 128
#define L_ 16
#define G_ 4
#define CPG_ 32
#define H_ 56
#define W_ 56
#define HW_ 3136

// Block = (b, t, g, htile, dy); 256 threads = 8 tx (w-segments of 8) x 32 ty.
// All 7 dx in-register: acc[7][8]. Window r[16] covers value cols [w0-4,w0+12);
// (p,dx) reads r[p+dx+1]. All float4 loads 16B-aligned (pad boundaries are
// multiples of 4 -> each 4-block fully valid or fully zero, masked).
// Explicit 2-deep software pipeline with NAMED frag buffers (no runtime
// indexing -> no scratch): load frag(c+1) while computing frag(c).
__global__ __launch_bounds__(256)
__attribute__((amdgpu_waves_per_eu(4, 4)))
void wcorr(const float* __restrict__ x, const float* __restrict__ wgt,
           float* __restrict__ out) {
  int bid = blockIdx.x;
  // bijective XCD swizzle: nwg = 7168 = 8 * 896; dy fastest so the 7
  // dy-siblings sharing input rows run adjacently on one XCD's L2.
  int wid = (bid & 7) * 896 + (bid >> 3);
  int dy = wid % 7;
  int rest = wid / 7;              // ((b*16 + t)*4 + g)*2 + htile
  int htile = rest & 1; rest >>= 1;
  int g = rest & 3;     rest >>= 2;
  int t = rest & 15;
  int b = rest >> 4;

  int tid = threadIdx.x;
  int tx = tid & 7;                // 0..7 (tx==7 compute-duplicated, store-masked)
  int ty = tid >> 3;               // 0..31
  int h = htile * 32 + ty;
  if (h >= H_) return;             // whole-wave exit (htile=1, wave 3)

  bool wr = (tx < 7);
  int w0 = wr ? tx * 8 : 48;       // clamp idle lanes to a safe segment
  int hh = h + dy - 3;
  bool hv = (hh >= 0) && (hh < H_);
  int hhs = hv ? hh : 0;
  int t1 = (t > 0) ? (t - 1) : 0;

  bool m0 = hv && (w0 >= 4);
  bool m1 = hv;
  bool m2 = hv;                    // w0+4 <= 52 always in-bounds
  bool m3 = hv && (w0 + 8 < W_);

  const size_t cstride = (size_t)L_ * HW_;
  const float* xbase = x + ((size_t)b * C_ + (size_t)g * CPG_) * cstride;
  const float* xs0 = xbase + (size_t)t * HW_ + (size_t)hhs * W_ + (w0 - 4);
  const float* x10 = xbase + (size_t)t1 * HW_ + (size_t)h * W_ + w0;
  const float* wg0 = wgt + (size_t)(g * CPG_) * (L_ * 49) + t * 49 + dy * 7;

  float acc[7][8];
  #pragma unroll
  for (int i = 0; i < 7; ++i)
    #pragma unroll
    for (int p = 0; p < 8; ++p) acc[i][p] = 0.0f;

  const float4 fz = make_float4(0.f, 0.f, 0.f, 0.f);
  const float sc = 1.0f / 32.0f;

#define LOAD_FRAG(Q0, Q1, Q2, Q3, A0, A1, W7, cc)                         \
  do {                                                                    \
    const float* xs_ = xs0 + (size_t)(cc) * cstride;                      \
    const float* x1_ = x10 + (size_t)(cc) * cstride;                      \
    Q0 = fz; Q1 = fz; Q2 = fz; Q3 = fz;                                   \
    if (m0) Q0 = *(const float4*)(xs_);                                   \
    if (m1) Q1 = *(const float4*)(xs_ + 4);                               \
    if (m2) Q2 = *(const float4*)(xs_ + 8);                               \
    if (m3) Q3 = *(const float4*)(xs_ + 12);                              \
    A0 = *(const float4*)(x1_);                                           \
    A1 = *(const float4*)(x1_ + 4);                                       \
    const float* wp_ = wg0 + (size_t)(cc) * (L_ * 49);                    \
    _Pragma("unroll")                                                     \
    for (int d_ = 0; d_ < 7; ++d_) W7[d_] = wp_[d_] * sc;                 \
  } while (0)

#define COMPUTE_FRAG(Q0, Q1, Q2, Q3, A0, A1, W7)                          \
  do {                                                                    \
    float r_[16] = {Q0.x, Q0.y, Q0.z, Q0.w, Q1.x, Q1.y, Q1.z, Q1.w,      \
                    Q2.x, Q2.y, Q2.z, Q2.w, Q3.x, Q3.y, Q3.z, Q3.w};     \
    float x1_[8] = {A0.x, A0.y, A0.z, A0.w, A1.x, A1.y, A1.z, A1.w};     \
    _Pragma("unroll")                                                     \
    for (int dxx_ = 0; dxx_ < 7; ++dxx_) {                                \
      _Pragma("unroll")                                                   \
      for (int p_ = 0; p_ < 8; ++p_) {                                    \
        acc[dxx_][p_] = fmaf(W7[dxx_], x1_[p_] * r_[p_ + dxx_ + 1],      \
                             acc[dxx_][p_]);                              \
      }                                                                   \
    }                                                                     \
  } while (0)

  float4 Aq0, Aq1, Aq2, Aq3, Aa0, Aa1;
  float4 Bq0, Bq1, Bq2, Bq3, Ba0, Ba1;
  float wA[7], wB[7];

  LOAD_FRAG(Aq0, Aq1, Aq2, Aq3, Aa0, Aa1, wA, 0);

  #pragma unroll 1
  for (int c = 0; c < CPG_; c += 2) {
    LOAD_FRAG(Bq0, Bq1, Bq2, Bq3, Ba0, Ba1, wB, c + 1);
    COMPUTE_FRAG(Aq0, Aq1, Aq2, Aq3, Aa0, Aa1, wA);
    int cn = (c + 2 < CPG_) ? (c + 2) : 0;   // clamped dummy reload on last trip
    LOAD_FRAG(Aq0, Aq1, Aq2, Aq3, Aa0, Aa1, wA, cn);
    COMPUTE_FRAG(Bq0, Bq1, Bq2, Bq3, Ba0, Ba1, wB);
  }

#undef LOAD_FRAG
#undef COMPUTE_FRAG

  if (wr) {
    #pragma unroll
    for (int dxx = 0; dxx < 7; ++dxx) {
      int och = (dy * 7 + dxx) * G_ + g;
      float* op = out + (((size_t)b * 196 + och) * L_ + t) * (size_t)HW_
                      + (size_t)h * W_ + w0;
      float4 o0 = make_float4(acc[dxx][0], acc[dxx][1],
                              acc[dxx][2], acc[dxx][3]);
      float4 o1 = make_float4(acc[dxx][4], acc[dxx][5],
                              acc[dxx][6], acc[dxx][7]);
      *(float4*)op = o0;
      *(float4*)(op + 4) = o1;
    }
  }
}

extern "C" void kernel_launch(void* const* d_in, const int* in_sizes, int n_in,
                              void* d_out, int out_size, void* d_ws, size_t ws_size,
                              hipStream_t stream) {
  const float* x = (const float*)d_in[0];
  const float* w = (const float*)d_in[1];
  float* o = (float*)d_out;
  dim3 grid(7168), block(256);
  hipLaunchKernelGGL(wcorr, grid, block, 0, stream, x, w, o);
}

// Round 7
// 276.316 us; speedup vs baseline: 1.8433x; 1.8433x over previous
//
#include <hip/hip_runtime.h>
#include <cstdint>

#define C_ 128
#define L_ 16
#define G_ 4
#define CPG_ 32
#define H_ 56
#define W_ 56
#define HW_ 3136

typedef float f4 __attribute__((ext_vector_type(4)));   // native vec for builtins

// Block = (b, t, g, htile, dy); 256 threads = 8 tx (w-segments of 8) x 32 ty.
// All 7 dx in-register: acc[7][8]. Window r[16] covers value cols [w0-4,w0+12);
// (p,dx) reads r[p+dx+1]. All f4 loads 16B-aligned (spatial pad boundaries
// are multiples of 4 -> each 4-float block fully valid or fully zero, masked).
//
// __launch_bounds__(256, 2): min 2 waves/EU -> 256-VGPR budget. This is the
// only contract that empirically stops the allocator's squeeze-to-64 spill
// behavior (r1: 128 regs; r2/r4/r5 with waves_per_eu attrs: 64/60/64 + spills).
// With ~128 regs all 6 loads of a c-iteration stay in flight and unroll-2 lets
// the scheduler overlap iter c+1 loads with iter c's 112 VALU ops.
__global__ __launch_bounds__(256, 2)
void wcorr(const float* __restrict__ x, const float* __restrict__ wgt,
           float* __restrict__ out) {
  int bid = blockIdx.x;
  // bijective XCD swizzle: nwg = 7168 = 8 * 896; dy fastest so the 7
  // dy-siblings sharing input rows run adjacently on one XCD's L2.
  int wid = (bid & 7) * 896 + (bid >> 3);
  int dy = wid % 7;
  int rest = wid / 7;              // ((b*16 + t)*4 + g)*2 + htile
  int htile = rest & 1; rest >>= 1;
  int g = rest & 3;     rest >>= 2;
  int t = rest & 15;
  int b = rest >> 4;

  int tid = threadIdx.x;
  int tx = tid & 7;                // 0..7 (tx==7 compute-duplicated, store-masked)
  int ty = tid >> 3;               // 0..31
  int h = htile * 32 + ty;
  if (h >= H_) return;             // whole-wave exit (htile=1, wave 3)

  bool wr = (tx < 7);
  int w0 = wr ? tx * 8 : 48;       // clamp idle lanes to a safe segment
  int hh = h + dy - 3;
  bool hv = (hh >= 0) && (hh < H_);
  int hhs = hv ? hh : 0;
  int t1 = (t > 0) ? (t - 1) : 0;

  // validity of the four 4-col blocks at value cols w0-4, w0, w0+4, w0+8
  bool m0 = hv && (w0 >= 4);
  bool m1 = hv;
  bool m2 = hv;                    // w0+4 <= 52 always in-bounds
  bool m3 = hv && (w0 + 8 < W_);

  const size_t cstride = (size_t)L_ * HW_;
  const float* xbase = x + ((size_t)b * C_ + (size_t)g * CPG_) * cstride;
  const float* xs0 = xbase + (size_t)t * HW_ + (size_t)hhs * W_ + (w0 - 4);
  const float* x10 = xbase + (size_t)t1 * HW_ + (size_t)h * W_ + w0;
  const float* wg0 = wgt + (size_t)(g * CPG_) * (L_ * 49) + t * 49 + dy * 7;

  float acc[7][8];
  #pragma unroll
  for (int i = 0; i < 7; ++i)
    #pragma unroll
    for (int p = 0; p < 8; ++p) acc[i][p] = 0.0f;

  const float sc = 1.0f / 32.0f;

  #pragma unroll 2
  for (int c = 0; c < CPG_; ++c) {
    // issue all global loads first, then the (wave-uniform -> s_load) weights
    const float* xs = xs0 + (size_t)c * cstride;
    const float* x1p = x10 + (size_t)c * cstride;
    f4 q0 = (f4)(0.0f);
    f4 q1 = q0, q2 = q0, q3 = q0;
    if (m0) q0 = *(const f4*)(xs);
    if (m1) q1 = *(const f4*)(xs + 4);
    if (m2) q2 = *(const f4*)(xs + 8);
    if (m3) q3 = *(const f4*)(xs + 12);
    f4 a0 = *(const f4*)(x1p);
    f4 a1 = *(const f4*)(x1p + 4);

    const float* wp = wg0 + (size_t)c * (L_ * 49);
    float w7[7];
    #pragma unroll
    for (int d = 0; d < 7; ++d) w7[d] = wp[d] * sc;   // fold 1/32 here

    float r[16] = {q0.x, q0.y, q0.z, q0.w, q1.x, q1.y, q1.z, q1.w,
                   q2.x, q2.y, q2.z, q2.w, q3.x, q3.y, q3.z, q3.w};
    float x1v[8] = {a0.x, a0.y, a0.z, a0.w, a1.x, a1.y, a1.z, a1.w};

    // output position w0+p, offset dx reads value col (w0+p)+dx-3 -> r[p+dx+1]
    #pragma unroll
    for (int dxx = 0; dxx < 7; ++dxx) {
      #pragma unroll
      for (int p = 0; p < 8; ++p) {
        acc[dxx][p] = fmaf(w7[dxx], x1v[p] * r[p + dxx + 1], acc[dxx][p]);
      }
    }
  }

  if (wr) {
    #pragma unroll
    for (int dxx = 0; dxx < 7; ++dxx) {
      int och = (dy * 7 + dxx) * G_ + g;
      float* op = out + (((size_t)b * 196 + och) * L_ + t) * (size_t)HW_
                      + (size_t)h * W_ + w0;
      f4 o0 = {acc[dxx][0], acc[dxx][1], acc[dxx][2], acc[dxx][3]};
      f4 o1 = {acc[dxx][4], acc[dxx][5], acc[dxx][6], acc[dxx][7]};
      __builtin_nontemporal_store(o0, (f4*)op);        // streaming output:
      __builtin_nontemporal_store(o1, (f4*)(op + 4));  // don't evict x in L2
    }
  }
}

extern "C" void kernel_launch(void* const* d_in, const int* in_sizes, int n_in,
                              void* d_out, int out_size, void* d_ws, size_t ws_size,
                              hipStream_t stream) {
  const float* x = (const float*)d_in[0];
  const float* w = (const float*)d_in[1];
  float* o = (float*)d_out;
  dim3 grid(7168), block(256);
  hipLaunchKernelGGL(wcorr, grid, block, 0, stream, x, w, o);
}